// Round 9
// baseline (27.073 us; speedup 1.0000x reference)
//
#include <hip/hip_runtime.h>

// Output layout (flat float32, reference return order):
//   out0: voxel_features  [N, 4]
//   out1: voxel_coords    [N, 4]   (int values written as float)
//   out2: patch_center_xyz[V, 3]
//   out3: patch_num_list  [B]      (int values written as float)
//
// SINGLE dispatch, 2048 persistent blocks (8/CU), perfectly balanced:
// every block = 128-voxel pipelined mean + own-patch coords scatter.
// No LDS scan: with ~1 patch/block we only need the patch's voxel range
// [vBeg, vEnd) = [sum(counts[0..p)), +counts[p]) -> one block REDUCTION
// (16 B LDS, 1 barrier), and the scatter writes a constant patch id.

__device__ __forceinline__ void reduce_store(
    float4 a0, float4 a1, float4 a2, float4 a3,
    int np, int t, int voxel, float4* __restrict__ out0)
{
    float sx = a0.x + a1.x + a2.x + a3.x;
    float sy = a0.y + a1.y + a2.y + a3.y;
    float sz = a0.z + a1.z + a2.z + a3.z;
    float sw = a0.w + a1.w + a2.w + a3.w;
#pragma unroll
    for (int m = 4; m; m >>= 1) {            // xor 4,2,1: stays in 8-lane group
        sx += __shfl_xor(sx, m);
        sy += __shfl_xor(sy, m);
        sz += __shfl_xor(sz, m);
        sw += __shfl_xor(sw, m);
    }
    if (t == 0) {
        float inv = 1.0f / fmaxf((float)np, 1.0f);
        out0[voxel] = make_float4(sx * inv, sy * inv, sz * inv, sw * inv);
    }
}

__global__ __launch_bounds__(256) void fused_bal_kernel(
    const float4* __restrict__ pv,     // [N*32] float4  (N,32,4)
    const int*    __restrict__ npts,   // [N]
    const int4*   __restrict__ coords, // [N]
    const int*    __restrict__ counts, // [P]
    const float*  __restrict__ centers,// [V,2]
    const int*    __restrict__ nums,   // [B]
    float4* __restrict__ out0,         // [N] features
    float4* __restrict__ out1,         // [N] coords-as-float
    float*  __restrict__ out2,         // [V,3]
    float*  __restrict__ out3,         // [B]
    int n_voxels, int P, int V, int B, int ppb)
{
    __shared__ int s_wsum[4];

    const int b   = blockIdx.x;
    const int tid = threadIdx.x;
    const int t   = tid & 7;            // lane within 8-lane voxel group
    const int g   = tid >> 3;           // voxel group 0..31 within block-iter

    const int vbase = b * 128;

    // ---- iteration 0: issue pv loads immediately ----
    float4 a0, a1, a2, a3;
    int npA = 0;
    {
        int v0i = vbase + g;
        if (v0i < n_voxels) {
            const float4* base = pv + (size_t)v0i * 32;
            a0 = base[t]; a1 = base[t + 8]; a2 = base[t + 16]; a3 = base[t + 24];
            npA = npts[v0i];             // same-address per group: broadcast
        }
    }

    // ---- own-patch range via block REDUCTION (hidden under loads) ----
    const int pBeg = b * ppb;
    if (pBeg < P) {
        const int pEnd = min(pBeg + ppb, P);
        // vBeg = sum(counts[0..pBeg))
        int s = 0;
        for (int i = tid; i < pBeg; i += 256) s += counts[i];
        const int lane = tid & 63;
        const int wave = tid >> 6;
#pragma unroll
        for (int m = 32; m; m >>= 1) s += __shfl_xor(s, m);
        if (lane == 0) s_wsum[wave] = s;
        __syncthreads();
        int vBeg = s_wsum[0] + s_wsum[1] + s_wsum[2] + s_wsum[3];

        // sequential over the (ppb, normally 1) owned patches
        for (int p = pBeg; p < pEnd; ++p) {
            int vEnd = vBeg + counts[p];     // L1-hot broadcast read
            float pf = (float)p;
            for (int j = vBeg + tid; j < vEnd; j += 256) {
                int4 c = coords[j];
                out1[j] = make_float4(pf, (float)c.y, (float)c.z, (float)c.w);
            }
            vBeg = vEnd;
        }
    }

    // ---- tiny outputs on block 0 ----
    if (b == 0) {
        for (int i = tid; i < V; i += 256) {
            out2[3 * i + 0] = centers[2 * i + 0];
            out2[3 * i + 1] = centers[2 * i + 1];
            out2[3 * i + 2] = 0.0f;
        }
        for (int i = tid; i < B; i += 256) out3[i] = (float)nums[i];
    }

    // ---- software-pipelined mean loop: 4 iterations of 32 voxels ----
#pragma unroll
    for (int it = 0; it < 4; ++it) {
        float4 b0, b1, b2, b3;
        int npB = 0;
        int vNext = vbase + (it + 1) * 32 + g;
        bool okN = (it < 3) && (vNext < n_voxels);
        if (okN) {                       // issue next iter's loads FIRST
            const float4* base = pv + (size_t)vNext * 32;
            b0 = base[t]; b1 = base[t + 8]; b2 = base[t + 16]; b3 = base[t + 24];
            npB = npts[vNext];
        }
        int vCur = vbase + it * 32 + g;
        if (vCur < n_voxels) {
            reduce_store(a0, a1, a2, a3, npA, t, vCur, out0);
        }
        a0 = b0; a1 = b1; a2 = b2; a3 = b3;   // renamed away by unroll
        npA = npB;
    }
}

extern "C" void kernel_launch(void* const* d_in, const int* in_sizes, int n_in,
                              void* d_out, int out_size, void* d_ws, size_t ws_size,
                              hipStream_t stream) {
    const float* pv      = (const float*)d_in[0];  // [N,32,4]
    const int*   npts    = (const int*)d_in[1];    // [N]
    const int*   coords  = (const int*)d_in[2];    // [N,4]
    const int*   pcounts = (const int*)d_in[3];    // [P]
    const float* centers = (const float*)d_in[4];  // [V,2]
    const int*   vnums   = (const int*)d_in[5];    // [B]

    const int N = in_sizes[1];       // 262144 voxels
    const int P = in_sizes[3];       // 2048 patches
    const int V = in_sizes[4] / 2;   // 2048 centers
    const int B = in_sizes[5];       // 4

    float* out0 = (float*)d_out;
    float* out1 = out0 + (size_t)N * 4;
    float* out2 = out1 + (size_t)N * 4;
    float* out3 = out2 + (size_t)V * 3;

    const int blocks = (N + 127) / 128;            // 2048 = 8/CU x 256 CU
    const int ppb    = (P + blocks - 1) / blocks;  // 1

    fused_bal_kernel<<<blocks, 256, 0, stream>>>(
        (const float4*)pv, npts, (const int4*)coords, pcounts, centers, vnums,
        (float4*)out0, (float4*)out1, out2, out3,
        N, P, V, B, ppb);
}